// Round 6
// baseline (183.932 us; speedup 1.0000x reference)
//
#include <hip/hip_runtime.h>
#include <hip/hip_bf16.h>

#define N_NODES 100000
#define N_EDGES 1250000
#define N_GRAPHS 512
#define F_IN 16
#define HID 64
#define EPS 1e-5f

#define K_B 1563        // buckets of 64 nodes: ceil(100000/64)
#define B_H 500         // histogram blocks
#define EPB 2500        // edges per histogram block (500*2500 = 1.25M exact)
#define M_SC (K_B * B_H)  // scan length = 781500

typedef unsigned int uint;

// ---- bf16 helpers (RNE pack, shift-unpack) ----
__device__ __forceinline__ uint f2bf(float f) {
    uint u = __float_as_uint(f);
    return (u + 0x7fffu + ((u >> 16) & 1u)) >> 16;
}
__device__ __forceinline__ uint pack2(float lo, float hi) {
    return f2bf(lo) | (f2bf(hi) << 16);
}
__device__ __forceinline__ void unpack8(float* o, uint4 v) {
    o[0] = __uint_as_float(v.x << 16); o[1] = __uint_as_float(v.x & 0xffff0000u);
    o[2] = __uint_as_float(v.y << 16); o[3] = __uint_as_float(v.y & 0xffff0000u);
    o[4] = __uint_as_float(v.z << 16); o[5] = __uint_as_float(v.z & 0xffff0000u);
    o[6] = __uint_as_float(v.w << 16); o[7] = __uint_as_float(v.w & 0xffff0000u);
}
__device__ __forceinline__ void accum8(float* a, uint4 v) {
    a[0] += __uint_as_float(v.x << 16); a[1] += __uint_as_float(v.x & 0xffff0000u);
    a[2] += __uint_as_float(v.y << 16); a[3] += __uint_as_float(v.y & 0xffff0000u);
    a[4] += __uint_as_float(v.z << 16); a[5] += __uint_as_float(v.z & 0xffff0000u);
    a[6] += __uint_as_float(v.w << 16); a[7] += __uint_as_float(v.w & 0xffff0000u);
}

// ---------------- CSR build: atomic-free counting sort ----------------

// per-block LDS histogram over coarse buckets; block 0 also zeroes stats
__global__ __launch_bounds__(256) void k_hist(const int4* __restrict__ dst4,
                                              int* __restrict__ hist,
                                              float* __restrict__ statsr) {
    __shared__ int h[K_B];
    int t = threadIdx.x, b = blockIdx.x;
    if (b == 0) {
        for (int i = t; i < 6 * 512; i += 256) statsr[i] = 0.f;
    }
    for (int k = t; k < K_B; k += 256) h[k] = 0;
    __syncthreads();
    const int4* d4 = dst4 + b * (EPB / 4);
    for (int i = t; i < EPB / 4; i += 256) {
        int4 d = d4[i];
        atomicAdd(&h[d.x >> 6], 1);
        atomicAdd(&h[d.y >> 6], 1);
        atomicAdd(&h[d.z >> 6], 1);
        atomicAdd(&h[d.w >> 6], 1);
    }
    __syncthreads();
    for (int k = t; k < K_B; k += 256) hist[k * B_H + b] = h[k];  // bucket-major
}

// hierarchical exclusive scan (1024 elems/block); bsum applied by consumers
__global__ void k_s1(const int* __restrict__ in, int* __restrict__ out,
                     int* __restrict__ bsum, int n) {
    __shared__ int sh[256];
    int blk = blockIdx.x, t = threadIdx.x;
    int base = blk * 1024 + t * 4;
    int v[4];
#pragma unroll
    for (int j = 0; j < 4; j++) { int i = base + j; v[j] = (i < n) ? in[i] : 0; }
    int tsum = v[0] + v[1] + v[2] + v[3];
    sh[t] = tsum;
    __syncthreads();
    for (int ofs = 1; ofs < 256; ofs <<= 1) {
        int x = (t >= ofs) ? sh[t - ofs] : 0;
        __syncthreads();
        sh[t] += x;
        __syncthreads();
    }
    int run = sh[t] - tsum;
    if (t == 255) bsum[blk] = sh[255];
#pragma unroll
    for (int j = 0; j < 4; j++) { int i = base + j; if (i < n) out[i] = run; run += v[j]; }
}

// exclusive scan of up to 1024 block sums, 256 threads x 4
__global__ void k_s2(int* __restrict__ bsum, int nb) {
    __shared__ int sh[256];
    int t = threadIdx.x;
    int v[4]; int s = 0;
#pragma unroll
    for (int j = 0; j < 4; j++) { int i = t * 4 + j; v[j] = (i < nb) ? bsum[i] : 0; s += v[j]; }
    sh[t] = s;
    __syncthreads();
    for (int ofs = 1; ofs < 256; ofs <<= 1) {
        int x = (t >= ofs) ? sh[t - ofs] : 0;
        __syncthreads();
        sh[t] += x;
        __syncthreads();
    }
    int run = sh[t] - s;
#pragma unroll
    for (int j = 0; j < 4; j++) { int i = t * 4 + j; if (i < nb) bsum[i] = run; run += v[j]; }
}

// place edges into bucket-sorted array via LDS counters (disjoint global ranges)
__global__ __launch_bounds__(256) void k_bucketize(const int4* __restrict__ src4,
        const int4* __restrict__ dst4, const int* __restrict__ ebase,
        const int* __restrict__ bsum, int* __restrict__ ebuck) {
    __shared__ int base[K_B];
    int t = threadIdx.x, b = blockIdx.x;
    for (int k = t; k < K_B; k += 256) {
        int idx = k * B_H + b;
        base[k] = ebase[idx] + bsum[idx >> 10];
    }
    __syncthreads();
    const int4* s4 = src4 + b * (EPB / 4);
    const int4* d4 = dst4 + b * (EPB / 4);
    for (int i = t; i < EPB / 4; i += 256) {
        int4 s = s4[i];
        int4 d = d4[i];
        int p;
        p = atomicAdd(&base[d.x >> 6], 1); ebuck[p] = s.x | ((d.x & 63) << 17);
        p = atomicAdd(&base[d.y >> 6], 1); ebuck[p] = s.y | ((d.y & 63) << 17);
        p = atomicAdd(&base[d.z >> 6], 1); ebuck[p] = s.z | ((d.z & 63) << 17);
        p = atomicAdd(&base[d.w >> 6], 1); ebuck[p] = s.w | ((d.w & 63) << 17);
    }
}

// per-bucket: single-pass via LDS edge buffer -> meta/dis + col
__global__ __launch_bounds__(256) void k_csr(const int* __restrict__ ebase,
        const int* __restrict__ bsum, const int* __restrict__ ebuck,
        int* __restrict__ col, int2* __restrict__ meta, float* __restrict__ dis) {
    int k = blockIdx.x, t = threadIdx.x;
    int i0 = k * B_H;
    int beg = ebase[i0] + bsum[i0 >> 10];
    int end;
    if (k + 1 < K_B) {
        int i1 = i0 + B_H;
        end = ebase[i1] + bsum[i1 >> 10];
    } else {
        end = N_EDGES;
    }
    int m = end - beg;
    __shared__ int eb[2048];
    __shared__ int c[64];
    __shared__ int sb[64];
    if (t < 64) c[t] = 0;
    __syncthreads();
    if (m <= 2048) {
        for (int i = t; i < m; i += 256) {
            int e = ebuck[beg + i];
            eb[i] = e;
            atomicAdd(&c[e >> 17], 1);
        }
    } else {
        for (int i = t; i < m; i += 256) atomicAdd(&c[ebuck[beg + i] >> 17], 1);
    }
    __syncthreads();
    if (t < 64) {
        int v = c[t];
        int incl = v;
#pragma unroll
        for (int o = 1; o < 64; o <<= 1) { int u = __shfl_up(incl, o); if (t >= o) incl += u; }
        int excl = incl - v;
        int node = k * 64 + t;
        if (node < N_NODES) {
            meta[node] = make_int2(beg + excl, v);
            dis[node] = rsqrtf((float)v + 1.0f);
        }
        sb[t] = beg + excl;
    }
    __syncthreads();
    if (m <= 2048) {
        for (int i = t; i < m; i += 256) {
            int e = eb[i];
            int pos = atomicAdd(&sb[e >> 17], 1);
            col[pos] = e & 0x1FFFF;
        }
    } else {
        for (int i = t; i < m; i += 256) {
            int e = ebuck[beg + i];
            int pos = atomicAdd(&sb[e >> 17], 1);
            col[pos] = e & 0x1FFFF;
        }
    }
}

// ---------------- dense compute ----------------

// A = (x @ W1) * dis[n], bf16 out.  32 nodes/block, 512 thr
__global__ __launch_bounds__(512) void k_gemm1(const float* __restrict__ x,
        const float* __restrict__ W1, const float* __restrict__ dis,
        ushort* __restrict__ A) {
    __shared__ float Ws[F_IN * HID];
    __shared__ float xs[32 * F_IN];
    int t = threadIdx.x;
    Ws[t] = W1[t];
    Ws[t + 512] = W1[t + 512];
    int n0 = blockIdx.x * 32;
    xs[t] = x[n0 * F_IN + t];
    __syncthreads();
    int f = t & 63, w = t >> 6;
    float Wreg[F_IN];
#pragma unroll
    for (int k = 0; k < F_IN; k++) Wreg[k] = Ws[k * HID + f];
#pragma unroll
    for (int i = 0; i < 4; i++) {
        int nl = w * 4 + i;
        float acc = 0.f;
#pragma unroll
        for (int kq = 0; kq < 4; kq++) {
            const float4 xv = *(const float4*)&xs[nl * F_IN + kq * 4];
            acc = fmaf(xv.x, Wreg[4 * kq + 0], acc);
            acc = fmaf(xv.y, Wreg[4 * kq + 1], acc);
            acc = fmaf(xv.z, Wreg[4 * kq + 2], acc);
            acc = fmaf(xv.w, Wreg[4 * kq + 3], acc);
        }
        int n = n0 + nl;
        A[(size_t)n * HID + f] = (ushort)f2bf(acc * dis[n]);
    }
}

// A2 = (prelu(bn(B)) @ W2) * dis[n]; bn scale/shift computed in prologue from
// replicated sums. bf16 in/out. 32 nodes/block, 512 thr
__global__ __launch_bounds__(512) void k_gemm2(const ushort* __restrict__ B,
        const float* __restrict__ s1r, const float* __restrict__ ss1r,
        const float* __restrict__ bnw, const float* __restrict__ bnb,
        const float* __restrict__ alpha, const float* __restrict__ W2,
        const float* __restrict__ dis, ushort* __restrict__ A2) {
    __shared__ float Ws[HID * HID];
    __shared__ float xs[32 * HID];
    __shared__ float scs[64], shsv[64];
    int t = threadIdx.x;
#pragma unroll
    for (int i = 0; i < 8; i++) Ws[i * 512 + t] = W2[i * 512 + t];
    if (t < 64) {
        float s = 0, q = 0;
#pragma unroll
        for (int r = 0; r < 8; r++) { s += s1r[r * 64 + t]; q += ss1r[r * 64 + t]; }
        const float invn = 1.f / N_NODES;
        float m = s * invn;
        float v = q * invn - m * m;
        float sc = bnw[t] * rsqrtf(v + EPS);
        scs[t] = sc;
        shsv[t] = bnb[t] - m * sc;
    }
    __syncthreads();
    int n0 = blockIdx.x * 32;
    float al = alpha[0];
    {
        const uint* Bu = (const uint*)(B + (size_t)n0 * HID);
#pragma unroll
        for (int i = 0; i < 2; i++) {
            int idx = i * 512 + t;
            uint u = Bu[idx];
            int fp = (idx & 31) * 2;
            int row = idx >> 5;
            float lo = __uint_as_float(u << 16) * scs[fp] + shsv[fp];
            float hi = __uint_as_float(u & 0xffff0000u) * scs[fp + 1] + shsv[fp + 1];
            lo = lo >= 0.f ? lo : al * lo;
            hi = hi >= 0.f ? hi : al * hi;
            xs[row * HID + fp] = lo;
            xs[row * HID + fp + 1] = hi;
        }
    }
    __syncthreads();
    int f = t & 63, w = t >> 6;
    float Wreg[HID];
#pragma unroll
    for (int k = 0; k < HID; k++) Wreg[k] = Ws[k * HID + f];
#pragma unroll
    for (int i = 0; i < 4; i++) {
        int nl = w * 4 + i;
        float acc = 0.f;
#pragma unroll
        for (int kq = 0; kq < 16; kq++) {
            const float4 xv = *(const float4*)&xs[nl * HID + kq * 4];
            acc = fmaf(xv.x, Wreg[4 * kq + 0], acc);
            acc = fmaf(xv.y, Wreg[4 * kq + 1], acc);
            acc = fmaf(xv.z, Wreg[4 * kq + 2], acc);
            acc = fmaf(xv.w, Wreg[4 * kq + 3], acc);
        }
        int n = n0 + nl;
        A2[(size_t)n * HID + f] = (ushort)f2bf(acc * dis[n]);
    }
}

// GCN aggregation + fused BN column stats.
// outB[n] = bf16( bias + dis[n]*(Asc[n] + sum_e Asc[col[e]]) )
// 8 lanes/node, 32 nodes/block; 8-edge unroll for MLP.
__global__ __launch_bounds__(256) void k_agg(const uint4* __restrict__ Asc,
        const float* __restrict__ dis, const int2* __restrict__ meta,
        const int* __restrict__ col, const float* __restrict__ bias,
        uint4* __restrict__ outB, float* __restrict__ sumr,
        float* __restrict__ sumsqr) {
    int t = threadIdx.x;
    int nid = blockIdx.x * 32 + (t >> 3);
    int fq = t & 7;
    int2 mt = meta[nid];
    int beg = mt.x, m = mt.y;
    float acc[8] = {0, 0, 0, 0, 0, 0, 0, 0};
    int j = 0;
    for (; j + 8 <= m; j += 8) {
        int s0 = col[beg + j];
        int s1 = col[beg + j + 1];
        int s2 = col[beg + j + 2];
        int s3 = col[beg + j + 3];
        int s4 = col[beg + j + 4];
        int s5 = col[beg + j + 5];
        int s6 = col[beg + j + 6];
        int s7 = col[beg + j + 7];
        uint4 r0 = Asc[(size_t)s0 * 8 + fq];
        uint4 r1 = Asc[(size_t)s1 * 8 + fq];
        uint4 r2 = Asc[(size_t)s2 * 8 + fq];
        uint4 r3 = Asc[(size_t)s3 * 8 + fq];
        uint4 r4 = Asc[(size_t)s4 * 8 + fq];
        uint4 r5 = Asc[(size_t)s5 * 8 + fq];
        uint4 r6 = Asc[(size_t)s6 * 8 + fq];
        uint4 r7 = Asc[(size_t)s7 * 8 + fq];
        accum8(acc, r0); accum8(acc, r1); accum8(acc, r2); accum8(acc, r3);
        accum8(acc, r4); accum8(acc, r5); accum8(acc, r6); accum8(acc, r7);
    }
    for (; j + 2 <= m; j += 2) {
        int s0 = col[beg + j];
        int s1 = col[beg + j + 1];
        uint4 r0 = Asc[(size_t)s0 * 8 + fq];
        uint4 r1 = Asc[(size_t)s1 * 8 + fq];
        accum8(acc, r0); accum8(acc, r1);
    }
    if (j < m) {
        int s = col[beg + j];
        accum8(acc, Asc[(size_t)s * 8 + fq]);
    }
    accum8(acc, Asc[(size_t)nid * 8 + fq]);   // self loop (row pre-scaled by dis)
    float dn = dis[nid];
    float4 b0 = ((const float4*)bias)[fq * 2];
    float4 b1 = ((const float4*)bias)[fq * 2 + 1];
    float o[8];
    o[0] = b0.x + dn * acc[0]; o[1] = b0.y + dn * acc[1];
    o[2] = b0.z + dn * acc[2]; o[3] = b0.w + dn * acc[3];
    o[4] = b1.x + dn * acc[4]; o[5] = b1.y + dn * acc[5];
    o[6] = b1.z + dn * acc[6]; o[7] = b1.w + dn * acc[7];
    uint4 ov;
    ov.x = pack2(o[0], o[1]); ov.y = pack2(o[2], o[3]);
    ov.z = pack2(o[4], o[5]); ov.w = pack2(o[6], o[7]);
    outB[(size_t)nid * 8 + fq] = ov;

    // fused column stats: reduce over the 8 nodes of this wave (lane bits 3,4,5)
    float sq[8];
#pragma unroll
    for (int i = 0; i < 8; i++) sq[i] = o[i] * o[i];
#pragma unroll
    for (int ofs = 8; ofs <= 32; ofs <<= 1) {
#pragma unroll
        for (int i = 0; i < 8; i++) {
            o[i] += __shfl_xor(o[i], ofs);
            sq[i] += __shfl_xor(sq[i], ofs);
        }
    }
    __shared__ float ps[4][64], pq[4][64];
    int w = t >> 6, lane = t & 63;
    if (lane < 8) {
#pragma unroll
        for (int i = 0; i < 8; i++) {
            ps[w][lane * 8 + i] = o[i];
            pq[w][lane * 8 + i] = sq[i];
        }
    }
    __syncthreads();
    if (t < 64) {
        float a = ps[0][t] + ps[1][t] + ps[2][t] + ps[3][t];
        float b = pq[0][t] + pq[1][t] + pq[2][t] + pq[3][t];
        int rep = (blockIdx.x & 7) * 64;
        atomicAdd(&sumr[rep + t], a);
        atomicAdd(&sumsqr[rep + t], b);
    }
}

// bn+prelu fused segment-max pooling + lin1 (t1 row = g_row @ lw1 + lb1) + bn3 stats
__global__ __launch_bounds__(256) void k_pool(const uint4* __restrict__ a,
        const float* __restrict__ s2r, const float* __restrict__ ss2r,
        const float* __restrict__ bnw, const float* __restrict__ bnb,
        const float* __restrict__ alpha, const float* __restrict__ lw1,
        const float* __restrict__ lb1, float* __restrict__ th,
        float* __restrict__ s3r, float* __restrict__ ss3r) {
    __shared__ float scs[64], shsv[64];
    __shared__ float sm[2048];
    __shared__ float gr[64];
    int gi = blockIdx.x;
    int t = threadIdx.x, rg = t >> 3, fq = t & 7;
    if (t < 64) {
        float s = 0, q = 0;
#pragma unroll
        for (int r = 0; r < 8; r++) { s += s2r[r * 64 + t]; q += ss2r[r * 64 + t]; }
        const float invn = 1.f / N_NODES;
        float m = s * invn;
        float v = q * invn - m * m;
        float sc = bnw[t] * rsqrtf(v + EPS);
        scs[t] = sc;
        shsv[t] = bnb[t] - m * sc;
    }
    __syncthreads();
    int lo = (gi * N_NODES + N_GRAPHS - 1) / N_GRAPHS;
    int hi = ((gi + 1) * N_NODES + N_GRAPHS - 1) / N_GRAPHS;
    float al = alpha[0];
    float sc[8], sh[8];
#pragma unroll
    for (int i = 0; i < 8; i++) { sc[i] = scs[fq * 8 + i]; sh[i] = shsv[fq * 8 + i]; }
    float mx[8];
#pragma unroll
    for (int i = 0; i < 8; i++) mx[i] = -INFINITY;
    for (int r = lo + rg; r < hi; r += 32) {
        float o[8];
        unpack8(o, a[(size_t)r * 8 + fq]);
#pragma unroll
        for (int i = 0; i < 8; i++) {
            float v = o[i] * sc[i] + sh[i];
            v = v >= 0.f ? v : al * v;
            mx[i] = fmaxf(mx[i], v);
        }
    }
#pragma unroll
    for (int i = 0; i < 8; i++) sm[rg * 64 + fq * 8 + i] = mx[i];
    __syncthreads();
    if (t < 64) {
        float m = sm[t];
#pragma unroll
        for (int i = 1; i < 32; i++) m = fmaxf(m, sm[i * 64 + t]);
        gr[t] = m;
    }
    __syncthreads();
    if (t < 64) {
        float acc = lb1[t];
#pragma unroll
        for (int k = 0; k < 64; k++) acc = fmaf(gr[k], lw1[k * 64 + t], acc);
        th[gi * 64 + t] = acc;
        int rep = (gi & 7) * 64;
        atomicAdd(&s3r[rep + t], acc);
        atomicAdd(&ss3r[rep + t], acc * acc);
    }
}

// head: bn3+prelu -> dot lw2 -> bn4+prelu -> out.  one block, 512 threads.
__global__ __launch_bounds__(512) void k_head(const float* __restrict__ th,
        const float* __restrict__ s3r, const float* __restrict__ ss3r,
        const float* __restrict__ bn3w, const float* __restrict__ bn3b,
        const float* __restrict__ a3, const float* __restrict__ lw2,
        const float* __restrict__ lb2, const float* __restrict__ bn4w,
        const float* __restrict__ bn4b, const float* __restrict__ a4,
        float* __restrict__ out) {
    int t = threadIdx.x, w = t >> 6, lane = t & 63;
    __shared__ float t2s[N_GRAPHS];
    __shared__ float rs[8], rq[8];
    const float invn = 1.f / N_GRAPHS;
    float s = 0, q = 0;
#pragma unroll
    for (int r = 0; r < 8; r++) { s += s3r[r * 64 + lane]; q += ss3r[r * 64 + lane]; }
    float m3 = s * invn;
    float v3 = q * invn - m3 * m3;
    float sc3 = bn3w[lane] * rsqrtf(v3 + EPS);
    float sh3 = bn3b[lane] - m3 * sc3;
    float al3 = a3[0];
    float wv = lw2[lane];
    float lb = lb2[0];
    for (int r = w; r < N_GRAPHS; r += 8) {
        float xv = th[r * 64 + lane] * sc3 + sh3;
        xv = xv >= 0.f ? xv : al3 * xv;
        float p = xv * wv;
#pragma unroll
        for (int o = 32; o > 0; o >>= 1) p += __shfl_xor(p, o);
        if (lane == 0) t2s[r] = p + lb;
    }
    __syncthreads();
    float tv = t2s[t];
    float ps = tv, pq = tv * tv;
#pragma unroll
    for (int o = 32; o > 0; o >>= 1) { ps += __shfl_xor(ps, o); pq += __shfl_xor(pq, o); }
    if (lane == 0) { rs[w] = ps; rq[w] = pq; }
    __syncthreads();
    float S = 0, Q = 0;
#pragma unroll
    for (int i = 0; i < 8; i++) { S += rs[i]; Q += rq[i]; }
    float m4 = S * invn;
    float v4 = Q * invn - m4 * m4;
    float sc4 = bn4w[0] * rsqrtf(v4 + EPS);
    float xb = (tv - m4) * sc4 + bn4b[0];
    float al4 = a4[0];
    out[t] = xb >= 0.f ? xb : al4 * xb;
}

extern "C" void kernel_launch(void* const* d_in, const int* in_sizes, int n_in,
                              void* d_out, int out_size, void* d_ws, size_t ws_size,
                              hipStream_t stream) {
    const float* x   = (const float*)d_in[0];
    const int*   ei  = (const int*)d_in[1];
    const int4*  src4 = (const int4*)ei;
    const int4*  dst4 = (const int4*)(ei + N_EDGES);
    const float* W1  = (const float*)d_in[3];
    const float* b1  = (const float*)d_in[4];
    const float* W2  = (const float*)d_in[5];
    const float* b2  = (const float*)d_in[6];
    const float* bn1w = (const float*)d_in[7];
    const float* bn1b = (const float*)d_in[8];
    const float* bn2w = (const float*)d_in[9];
    const float* bn2b = (const float*)d_in[10];
    const float* bn3w = (const float*)d_in[11];
    const float* bn3b = (const float*)d_in[12];
    const float* bn4w = (const float*)d_in[13];
    const float* bn4b = (const float*)d_in[14];
    const float* lw1  = (const float*)d_in[15];
    const float* lb1  = (const float*)d_in[16];
    const float* lw2  = (const float*)d_in[17];
    const float* lb2  = (const float*)d_in[18];
    const float* a1   = (const float*)d_in[19];
    const float* a2   = (const float*)d_in[20];
    const float* a3   = (const float*)d_in[21];
    const float* a4   = (const float*)d_in[22];
    float* out = (float*)d_out;

    char* p = (char*)d_ws;
    auto carve = [&](size_t bytes) -> void* {
        void* r = (void*)p;
        p += (bytes + 255) & ~(size_t)255;
        return r;
    };
    int*    hist = (int*)carve((size_t)M_SC * 4);
    int*    ebase = (int*)carve((size_t)M_SC * 4);
    int*    ebuck = (int*)carve((size_t)N_EDGES * 4);
    int*    col  = (int*)carve((size_t)N_EDGES * 4);
    float*  dis  = (float*)carve((size_t)N_NODES * 4);
    int2*   meta = (int2*)carve((size_t)N_NODES * 8);
    int*    bsum = (int*)carve(4096);
    ushort* A    = (ushort*)carve((size_t)N_NODES * HID * 2);
    ushort* B    = (ushort*)carve((size_t)N_NODES * HID * 2);
    float*  th   = (float*)carve((size_t)N_GRAPHS * HID * 4);
    float*  statsr = (float*)carve(6 * 512 * 4);   // 6 arrays x 8 replicas x 64
    float* s1r = statsr,          *ss1r = statsr + 512;
    float* s2r = statsr + 1024,   *ss2r = statsr + 1536;
    float* s3r = statsr + 2048,   *ss3r = statsr + 2560;

    const int SC_BLKS = (M_SC + 1023) / 1024;  // 764

    k_hist<<<B_H, 256, 0, stream>>>(dst4, hist, statsr);
    k_s1<<<SC_BLKS, 256, 0, stream>>>(hist, ebase, bsum, M_SC);
    k_s2<<<1, 256, 0, stream>>>(bsum, SC_BLKS);
    k_bucketize<<<B_H, 256, 0, stream>>>(src4, dst4, ebase, bsum, ebuck);
    k_csr<<<K_B, 256, 0, stream>>>(ebase, bsum, ebuck, col, meta, dis);

    const int NB32 = N_NODES / 32;  // 3125, exact
    k_gemm1<<<NB32, 512, 0, stream>>>(x, W1, dis, A);
    k_agg<<<NB32, 256, 0, stream>>>((const uint4*)A, dis, meta, col, b1, (uint4*)B,
                                    s1r, ss1r);
    k_gemm2<<<NB32, 512, 0, stream>>>(B, s1r, ss1r, bn1w, bn1b, a1, W2, dis, A);
    k_agg<<<NB32, 256, 0, stream>>>((const uint4*)A, dis, meta, col, b2, (uint4*)B,
                                    s2r, ss2r);
    k_pool<<<N_GRAPHS, 256, 0, stream>>>((const uint4*)B, s2r, ss2r, bn2w, bn2b, a2,
                                         lw1, lb1, th, s3r, ss3r);
    k_head<<<1, 512, 0, stream>>>(th, s3r, ss3r, bn3w, bn3b, a3, lw2, lb2,
                                  bn4w, bn4b, a4, out);
}

// Round 7
// 179.138 us; speedup vs baseline: 1.0268x; 1.0268x over previous
//
#include <hip/hip_runtime.h>
#include <hip/hip_bf16.h>

#define N_NODES 100000
#define N_EDGES 1250000
#define N_GRAPHS 512
#define F_IN 16
#define HID 64
#define EPS 1e-5f

#define K_B 1563        // buckets of 64 nodes: ceil(100000/64)
#define B_H 250         // histogram blocks
#define EPB 5000        // edges per histogram block (250*5000 = 1.25M exact)
#define M_SC (K_B * B_H)  // scan length = 390750

typedef unsigned int uint;

// ---- bf16 helpers (RNE pack, shift-unpack) ----
__device__ __forceinline__ uint f2bf(float f) {
    uint u = __float_as_uint(f);
    return (u + 0x7fffu + ((u >> 16) & 1u)) >> 16;
}
__device__ __forceinline__ uint pack2(float lo, float hi) {
    return f2bf(lo) | (f2bf(hi) << 16);
}
__device__ __forceinline__ void unpack8(float* o, uint4 v) {
    o[0] = __uint_as_float(v.x << 16); o[1] = __uint_as_float(v.x & 0xffff0000u);
    o[2] = __uint_as_float(v.y << 16); o[3] = __uint_as_float(v.y & 0xffff0000u);
    o[4] = __uint_as_float(v.z << 16); o[5] = __uint_as_float(v.z & 0xffff0000u);
    o[6] = __uint_as_float(v.w << 16); o[7] = __uint_as_float(v.w & 0xffff0000u);
}
__device__ __forceinline__ void accum8(float* a, uint4 v) {
    a[0] += __uint_as_float(v.x << 16); a[1] += __uint_as_float(v.x & 0xffff0000u);
    a[2] += __uint_as_float(v.y << 16); a[3] += __uint_as_float(v.y & 0xffff0000u);
    a[4] += __uint_as_float(v.z << 16); a[5] += __uint_as_float(v.z & 0xffff0000u);
    a[6] += __uint_as_float(v.w << 16); a[7] += __uint_as_float(v.w & 0xffff0000u);
}

// ---------------- CSR build: atomic-free counting sort ----------------

// per-block LDS histogram over coarse buckets; block 0 also zeroes stats
__global__ __launch_bounds__(256) void k_hist(const int4* __restrict__ dst4,
                                              int* __restrict__ hist,
                                              float* __restrict__ statsr) {
    __shared__ int h[K_B];
    int t = threadIdx.x, b = blockIdx.x;
    if (b == 0) {
        for (int i = t; i < 6 * 512; i += 256) statsr[i] = 0.f;
    }
    for (int k = t; k < K_B; k += 256) h[k] = 0;
    __syncthreads();
    const int4* d4 = dst4 + b * (EPB / 4);
    for (int i = t; i < EPB / 4; i += 256) {
        int4 d = d4[i];
        atomicAdd(&h[d.x >> 6], 1);
        atomicAdd(&h[d.y >> 6], 1);
        atomicAdd(&h[d.z >> 6], 1);
        atomicAdd(&h[d.w >> 6], 1);
    }
    __syncthreads();
    for (int k = t; k < K_B; k += 256) hist[k * B_H + b] = h[k];  // bucket-major
}

// hierarchical exclusive scan (1024 elems/block); bsum applied by consumers
__global__ void k_s1(const int* __restrict__ in, int* __restrict__ out,
                     int* __restrict__ bsum, int n) {
    __shared__ int sh[256];
    int blk = blockIdx.x, t = threadIdx.x;
    int base = blk * 1024 + t * 4;
    int v[4];
#pragma unroll
    for (int j = 0; j < 4; j++) { int i = base + j; v[j] = (i < n) ? in[i] : 0; }
    int tsum = v[0] + v[1] + v[2] + v[3];
    sh[t] = tsum;
    __syncthreads();
    for (int ofs = 1; ofs < 256; ofs <<= 1) {
        int x = (t >= ofs) ? sh[t - ofs] : 0;
        __syncthreads();
        sh[t] += x;
        __syncthreads();
    }
    int run = sh[t] - tsum;
    if (t == 255) bsum[blk] = sh[255];
#pragma unroll
    for (int j = 0; j < 4; j++) { int i = base + j; if (i < n) out[i] = run; run += v[j]; }
}

// exclusive scan of up to 1024 block sums, 256 threads x 4
__global__ void k_s2(int* __restrict__ bsum, int nb) {
    __shared__ int sh[256];
    int t = threadIdx.x;
    int v[4]; int s = 0;
#pragma unroll
    for (int j = 0; j < 4; j++) { int i = t * 4 + j; v[j] = (i < nb) ? bsum[i] : 0; s += v[j]; }
    sh[t] = s;
    __syncthreads();
    for (int ofs = 1; ofs < 256; ofs <<= 1) {
        int x = (t >= ofs) ? sh[t - ofs] : 0;
        __syncthreads();
        sh[t] += x;
        __syncthreads();
    }
    int run = sh[t] - s;
#pragma unroll
    for (int j = 0; j < 4; j++) { int i = t * 4 + j; if (i < nb) bsum[i] = run; run += v[j]; }
}

// place edges into bucket-sorted array via LDS counters (disjoint global ranges)
__global__ __launch_bounds__(256) void k_bucketize(const int4* __restrict__ src4,
        const int4* __restrict__ dst4, const int* __restrict__ ebase,
        const int* __restrict__ bsum, int* __restrict__ ebuck) {
    __shared__ int base[K_B];
    int t = threadIdx.x, b = blockIdx.x;
    for (int k = t; k < K_B; k += 256) {
        int idx = k * B_H + b;
        base[k] = ebase[idx] + bsum[idx >> 10];
    }
    __syncthreads();
    const int4* s4 = src4 + b * (EPB / 4);
    const int4* d4 = dst4 + b * (EPB / 4);
    for (int i = t; i < EPB / 4; i += 256) {
        int4 s = s4[i];
        int4 d = d4[i];
        int p;
        p = atomicAdd(&base[d.x >> 6], 1); ebuck[p] = s.x | ((d.x & 63) << 17);
        p = atomicAdd(&base[d.y >> 6], 1); ebuck[p] = s.y | ((d.y & 63) << 17);
        p = atomicAdd(&base[d.z >> 6], 1); ebuck[p] = s.z | ((d.z & 63) << 17);
        p = atomicAdd(&base[d.w >> 6], 1); ebuck[p] = s.w | ((d.w & 63) << 17);
    }
}

// per-bucket: counting sort by (node, src-octant) -> meta/dis + col sorted by src
// within each node's edge list (L2 working-set shaping for k_agg).
__global__ __launch_bounds__(256) void k_csr(const int* __restrict__ ebase,
        const int* __restrict__ bsum, const int* __restrict__ ebuck,
        int* __restrict__ col, int2* __restrict__ meta, float* __restrict__ dis) {
    int k = blockIdx.x, t = threadIdx.x;
    int i0 = k * B_H;
    int beg = ebase[i0] + bsum[i0 >> 10];
    int end;
    if (k + 1 < K_B) {
        int i1 = i0 + B_H;
        end = ebase[i1] + bsum[i1 >> 10];
    } else {
        end = N_EDGES;
    }
    int m = end - beg;
    __shared__ int eb[2048];
    __shared__ int cnt512[512];
    __shared__ int off512[512];
    __shared__ int sb[512];
    __shared__ int sh[256];
    for (int i = t; i < 512; i += 256) cnt512[i] = 0;
    __syncthreads();
    if (m <= 2048) {
        for (int i = t; i < m; i += 256) {
            int e = ebuck[beg + i];
            eb[i] = e;
            int bin = ((e >> 17) << 3) | ((e & 0x1FFFF) >> 14);
            atomicAdd(&cnt512[bin], 1);
        }
        __syncthreads();
        int v0 = cnt512[2 * t], v1 = cnt512[2 * t + 1];
        int pair = v0 + v1;
        sh[t] = pair;
        __syncthreads();
        for (int ofs = 1; ofs < 256; ofs <<= 1) {
            int x = (t >= ofs) ? sh[t - ofs] : 0;
            __syncthreads();
            sh[t] += x;
            __syncthreads();
        }
        int excl = sh[t] - pair;
        off512[2 * t] = excl;
        off512[2 * t + 1] = excl + v0;
        sb[2 * t] = beg + excl;
        sb[2 * t + 1] = beg + excl + v0;
        __syncthreads();
        if (t < 64) {
            int o0 = off512[t * 8];
            int o1 = (t < 63) ? off512[(t + 1) * 8] : m;
            int node = k * 64 + t;
            if (node < N_NODES) {
                meta[node] = make_int2(beg + o0, o1 - o0);
                dis[node] = rsqrtf((float)(o1 - o0) + 1.0f);
            }
        }
        __syncthreads();
        for (int i = t; i < m; i += 256) {
            int e = eb[i];
            int bin = ((e >> 17) << 3) | ((e & 0x1FFFF) >> 14);
            int pos = atomicAdd(&sb[bin], 1);
            col[pos] = e & 0x1FFFF;
        }
    } else {
        // fallback (unsorted within node) for oversized buckets
        for (int i = t; i < m; i += 256) atomicAdd(&cnt512[ebuck[beg + i] >> 17], 1);
        __syncthreads();
        if (t < 64) {
            int v = cnt512[t];
            int incl = v;
#pragma unroll
            for (int o = 1; o < 64; o <<= 1) { int u = __shfl_up(incl, o); if (t >= o) incl += u; }
            int excl = incl - v;
            int node = k * 64 + t;
            if (node < N_NODES) {
                meta[node] = make_int2(beg + excl, v);
                dis[node] = rsqrtf((float)v + 1.0f);
            }
            sb[t] = beg + excl;
        }
        __syncthreads();
        for (int i = t; i < m; i += 256) {
            int e = ebuck[beg + i];
            int pos = atomicAdd(&sb[e >> 17], 1);
            col[pos] = e & 0x1FFFF;
        }
    }
}

// ---------------- dense compute ----------------

// A = (x @ W1) * dis[n], bf16 out.  32 nodes/block, 512 thr
__global__ __launch_bounds__(512) void k_gemm1(const float* __restrict__ x,
        const float* __restrict__ W1, const float* __restrict__ dis,
        ushort* __restrict__ A) {
    __shared__ float Ws[F_IN * HID];
    __shared__ float xs[32 * F_IN];
    int t = threadIdx.x;
    Ws[t] = W1[t];
    Ws[t + 512] = W1[t + 512];
    int n0 = blockIdx.x * 32;
    xs[t] = x[n0 * F_IN + t];
    __syncthreads();
    int f = t & 63, w = t >> 6;
    float Wreg[F_IN];
#pragma unroll
    for (int k = 0; k < F_IN; k++) Wreg[k] = Ws[k * HID + f];
#pragma unroll
    for (int i = 0; i < 4; i++) {
        int nl = w * 4 + i;
        float acc = 0.f;
#pragma unroll
        for (int kq = 0; kq < 4; kq++) {
            const float4 xv = *(const float4*)&xs[nl * F_IN + kq * 4];
            acc = fmaf(xv.x, Wreg[4 * kq + 0], acc);
            acc = fmaf(xv.y, Wreg[4 * kq + 1], acc);
            acc = fmaf(xv.z, Wreg[4 * kq + 2], acc);
            acc = fmaf(xv.w, Wreg[4 * kq + 3], acc);
        }
        int n = n0 + nl;
        A[(size_t)n * HID + f] = (ushort)f2bf(acc * dis[n]);
    }
}

// A2 = (prelu(bn(B)) @ W2) * dis[n]; bn scale/shift computed in prologue from
// replicated sums. bf16 in/out. 32 nodes/block, 512 thr
__global__ __launch_bounds__(512) void k_gemm2(const ushort* __restrict__ B,
        const float* __restrict__ s1r, const float* __restrict__ ss1r,
        const float* __restrict__ bnw, const float* __restrict__ bnb,
        const float* __restrict__ alpha, const float* __restrict__ W2,
        const float* __restrict__ dis, ushort* __restrict__ A2) {
    __shared__ float Ws[HID * HID];
    __shared__ float xs[32 * HID];
    __shared__ float scs[64], shsv[64];
    int t = threadIdx.x;
#pragma unroll
    for (int i = 0; i < 8; i++) Ws[i * 512 + t] = W2[i * 512 + t];
    if (t < 64) {
        float s = 0, q = 0;
#pragma unroll
        for (int r = 0; r < 8; r++) { s += s1r[r * 64 + t]; q += ss1r[r * 64 + t]; }
        const float invn = 1.f / N_NODES;
        float m = s * invn;
        float v = q * invn - m * m;
        float sc = bnw[t] * rsqrtf(v + EPS);
        scs[t] = sc;
        shsv[t] = bnb[t] - m * sc;
    }
    __syncthreads();
    int n0 = blockIdx.x * 32;
    float al = alpha[0];
    {
        const uint* Bu = (const uint*)(B + (size_t)n0 * HID);
#pragma unroll
        for (int i = 0; i < 2; i++) {
            int idx = i * 512 + t;
            uint u = Bu[idx];
            int fp = (idx & 31) * 2;
            int row = idx >> 5;
            float lo = __uint_as_float(u << 16) * scs[fp] + shsv[fp];
            float hi = __uint_as_float(u & 0xffff0000u) * scs[fp + 1] + shsv[fp + 1];
            lo = lo >= 0.f ? lo : al * lo;
            hi = hi >= 0.f ? hi : al * hi;
            xs[row * HID + fp] = lo;
            xs[row * HID + fp + 1] = hi;
        }
    }
    __syncthreads();
    int f = t & 63, w = t >> 6;
    float Wreg[HID];
#pragma unroll
    for (int k = 0; k < HID; k++) Wreg[k] = Ws[k * HID + f];
#pragma unroll
    for (int i = 0; i < 4; i++) {
        int nl = w * 4 + i;
        float acc = 0.f;
#pragma unroll
        for (int kq = 0; kq < 16; kq++) {
            const float4 xv = *(const float4*)&xs[nl * HID + kq * 4];
            acc = fmaf(xv.x, Wreg[4 * kq + 0], acc);
            acc = fmaf(xv.y, Wreg[4 * kq + 1], acc);
            acc = fmaf(xv.z, Wreg[4 * kq + 2], acc);
            acc = fmaf(xv.w, Wreg[4 * kq + 3], acc);
        }
        int n = n0 + nl;
        A2[(size_t)n * HID + f] = (ushort)f2bf(acc * dis[n]);
    }
}

// GCN aggregation + fused BN column stats.
// outB[n] = bf16( bias + dis[n]*(Asc[n] + sum_e Asc[col[e]]) )
// 8 lanes/node, 32 nodes/block; 8-edge unroll for MLP.
__global__ __launch_bounds__(256) void k_agg(const uint4* __restrict__ Asc,
        const float* __restrict__ dis, const int2* __restrict__ meta,
        const int* __restrict__ col, const float* __restrict__ bias,
        uint4* __restrict__ outB, float* __restrict__ sumr,
        float* __restrict__ sumsqr) {
    int t = threadIdx.x;
    int nid = blockIdx.x * 32 + (t >> 3);
    int fq = t & 7;
    int2 mt = meta[nid];
    int beg = mt.x, m = mt.y;
    float acc[8] = {0, 0, 0, 0, 0, 0, 0, 0};
    int j = 0;
    for (; j + 8 <= m; j += 8) {
        int s0 = col[beg + j];
        int s1 = col[beg + j + 1];
        int s2 = col[beg + j + 2];
        int s3 = col[beg + j + 3];
        int s4 = col[beg + j + 4];
        int s5 = col[beg + j + 5];
        int s6 = col[beg + j + 6];
        int s7 = col[beg + j + 7];
        uint4 r0 = Asc[(size_t)s0 * 8 + fq];
        uint4 r1 = Asc[(size_t)s1 * 8 + fq];
        uint4 r2 = Asc[(size_t)s2 * 8 + fq];
        uint4 r3 = Asc[(size_t)s3 * 8 + fq];
        uint4 r4 = Asc[(size_t)s4 * 8 + fq];
        uint4 r5 = Asc[(size_t)s5 * 8 + fq];
        uint4 r6 = Asc[(size_t)s6 * 8 + fq];
        uint4 r7 = Asc[(size_t)s7 * 8 + fq];
        accum8(acc, r0); accum8(acc, r1); accum8(acc, r2); accum8(acc, r3);
        accum8(acc, r4); accum8(acc, r5); accum8(acc, r6); accum8(acc, r7);
    }
    for (; j + 2 <= m; j += 2) {
        int s0 = col[beg + j];
        int s1 = col[beg + j + 1];
        uint4 r0 = Asc[(size_t)s0 * 8 + fq];
        uint4 r1 = Asc[(size_t)s1 * 8 + fq];
        accum8(acc, r0); accum8(acc, r1);
    }
    if (j < m) {
        int s = col[beg + j];
        accum8(acc, Asc[(size_t)s * 8 + fq]);
    }
    accum8(acc, Asc[(size_t)nid * 8 + fq]);   // self loop (row pre-scaled by dis)
    float dn = dis[nid];
    float4 b0 = ((const float4*)bias)[fq * 2];
    float4 b1 = ((const float4*)bias)[fq * 2 + 1];
    float o[8];
    o[0] = b0.x + dn * acc[0]; o[1] = b0.y + dn * acc[1];
    o[2] = b0.z + dn * acc[2]; o[3] = b0.w + dn * acc[3];
    o[4] = b1.x + dn * acc[4]; o[5] = b1.y + dn * acc[5];
    o[6] = b1.z + dn * acc[6]; o[7] = b1.w + dn * acc[7];
    uint4 ov;
    ov.x = pack2(o[0], o[1]); ov.y = pack2(o[2], o[3]);
    ov.z = pack2(o[4], o[5]); ov.w = pack2(o[6], o[7]);
    outB[(size_t)nid * 8 + fq] = ov;

    // fused column stats: reduce over the 8 nodes of this wave (lane bits 3,4,5)
    float sq[8];
#pragma unroll
    for (int i = 0; i < 8; i++) sq[i] = o[i] * o[i];
#pragma unroll
    for (int ofs = 8; ofs <= 32; ofs <<= 1) {
#pragma unroll
        for (int i = 0; i < 8; i++) {
            o[i] += __shfl_xor(o[i], ofs);
            sq[i] += __shfl_xor(sq[i], ofs);
        }
    }
    __shared__ float ps[4][64], pq[4][64];
    int w = t >> 6, lane = t & 63;
    if (lane < 8) {
#pragma unroll
        for (int i = 0; i < 8; i++) {
            ps[w][lane * 8 + i] = o[i];
            pq[w][lane * 8 + i] = sq[i];
        }
    }
    __syncthreads();
    if (t < 64) {
        float a = ps[0][t] + ps[1][t] + ps[2][t] + ps[3][t];
        float b = pq[0][t] + pq[1][t] + pq[2][t] + pq[3][t];
        int rep = (blockIdx.x & 7) * 64;
        atomicAdd(&sumr[rep + t], a);
        atomicAdd(&sumsqr[rep + t], b);
    }
}

// bn+prelu fused segment-max pooling + lin1 (t1 row = g_row @ lw1 + lb1) + bn3 stats
__global__ __launch_bounds__(256) void k_pool(const uint4* __restrict__ a,
        const float* __restrict__ s2r, const float* __restrict__ ss2r,
        const float* __restrict__ bnw, const float* __restrict__ bnb,
        const float* __restrict__ alpha, const float* __restrict__ lw1,
        const float* __restrict__ lb1, float* __restrict__ th,
        float* __restrict__ s3r, float* __restrict__ ss3r) {
    __shared__ float scs[64], shsv[64];
    __shared__ float sm[2048];
    __shared__ float gr[64];
    int gi = blockIdx.x;
    int t = threadIdx.x, rg = t >> 3, fq = t & 7;
    if (t < 64) {
        float s = 0, q = 0;
#pragma unroll
        for (int r = 0; r < 8; r++) { s += s2r[r * 64 + t]; q += ss2r[r * 64 + t]; }
        const float invn = 1.f / N_NODES;
        float m = s * invn;
        float v = q * invn - m * m;
        float sc = bnw[t] * rsqrtf(v + EPS);
        scs[t] = sc;
        shsv[t] = bnb[t] - m * sc;
    }
    __syncthreads();
    int lo = (gi * N_NODES + N_GRAPHS - 1) / N_GRAPHS;
    int hi = ((gi + 1) * N_NODES + N_GRAPHS - 1) / N_GRAPHS;
    float al = alpha[0];
    float sc[8], sh[8];
#pragma unroll
    for (int i = 0; i < 8; i++) { sc[i] = scs[fq * 8 + i]; sh[i] = shsv[fq * 8 + i]; }
    float mx[8];
#pragma unroll
    for (int i = 0; i < 8; i++) mx[i] = -INFINITY;
    for (int r = lo + rg; r < hi; r += 32) {
        float o[8];
        unpack8(o, a[(size_t)r * 8 + fq]);
#pragma unroll
        for (int i = 0; i < 8; i++) {
            float v = o[i] * sc[i] + sh[i];
            v = v >= 0.f ? v : al * v;
            mx[i] = fmaxf(mx[i], v);
        }
    }
#pragma unroll
    for (int i = 0; i < 8; i++) sm[rg * 64 + fq * 8 + i] = mx[i];
    __syncthreads();
    if (t < 64) {
        float m = sm[t];
#pragma unroll
        for (int i = 1; i < 32; i++) m = fmaxf(m, sm[i * 64 + t]);
        gr[t] = m;
    }
    __syncthreads();
    if (t < 64) {
        float acc = lb1[t];
#pragma unroll
        for (int k = 0; k < 64; k++) acc = fmaf(gr[k], lw1[k * 64 + t], acc);
        th[gi * 64 + t] = acc;
        int rep = (gi & 7) * 64;
        atomicAdd(&s3r[rep + t], acc);
        atomicAdd(&ss3r[rep + t], acc * acc);
    }
}

// head: bn3+prelu -> dot lw2 -> bn4+prelu -> out.  one block, 512 threads.
__global__ __launch_bounds__(512) void k_head(const float* __restrict__ th,
        const float* __restrict__ s3r, const float* __restrict__ ss3r,
        const float* __restrict__ bn3w, const float* __restrict__ bn3b,
        const float* __restrict__ a3, const float* __restrict__ lw2,
        const float* __restrict__ lb2, const float* __restrict__ bn4w,
        const float* __restrict__ bn4b, const float* __restrict__ a4,
        float* __restrict__ out) {
    int t = threadIdx.x, w = t >> 6, lane = t & 63;
    __shared__ float t2s[N_GRAPHS];
    __shared__ float rs[8], rq[8];
    const float invn = 1.f / N_GRAPHS;
    float s = 0, q = 0;
#pragma unroll
    for (int r = 0; r < 8; r++) { s += s3r[r * 64 + lane]; q += ss3r[r * 64 + lane]; }
    float m3 = s * invn;
    float v3 = q * invn - m3 * m3;
    float sc3 = bn3w[lane] * rsqrtf(v3 + EPS);
    float sh3 = bn3b[lane] - m3 * sc3;
    float al3 = a3[0];
    float wv = lw2[lane];
    float lb = lb2[0];
    for (int r = w; r < N_GRAPHS; r += 8) {
        float xv = th[r * 64 + lane] * sc3 + sh3;
        xv = xv >= 0.f ? xv : al3 * xv;
        float p = xv * wv;
#pragma unroll
        for (int o = 32; o > 0; o >>= 1) p += __shfl_xor(p, o);
        if (lane == 0) t2s[r] = p + lb;
    }
    __syncthreads();
    float tv = t2s[t];
    float ps = tv, pq = tv * tv;
#pragma unroll
    for (int o = 32; o > 0; o >>= 1) { ps += __shfl_xor(ps, o); pq += __shfl_xor(pq, o); }
    if (lane == 0) { rs[w] = ps; rq[w] = pq; }
    __syncthreads();
    float S = 0, Q = 0;
#pragma unroll
    for (int i = 0; i < 8; i++) { S += rs[i]; Q += rq[i]; }
    float m4 = S * invn;
    float v4 = Q * invn - m4 * m4;
    float sc4 = bn4w[0] * rsqrtf(v4 + EPS);
    float xb = (tv - m4) * sc4 + bn4b[0];
    float al4 = a4[0];
    out[t] = xb >= 0.f ? xb : al4 * xb;
}

extern "C" void kernel_launch(void* const* d_in, const int* in_sizes, int n_in,
                              void* d_out, int out_size, void* d_ws, size_t ws_size,
                              hipStream_t stream) {
    const float* x   = (const float*)d_in[0];
    const int*   ei  = (const int*)d_in[1];
    const int4*  src4 = (const int4*)ei;
    const int4*  dst4 = (const int4*)(ei + N_EDGES);
    const float* W1  = (const float*)d_in[3];
    const float* b1  = (const float*)d_in[4];
    const float* W2  = (const float*)d_in[5];
    const float* b2  = (const float*)d_in[6];
    const float* bn1w = (const float*)d_in[7];
    const float* bn1b = (const float*)d_in[8];
    const float* bn2w = (const float*)d_in[9];
    const float* bn2b = (const float*)d_in[10];
    const float* bn3w = (const float*)d_in[11];
    const float* bn3b = (const float*)d_in[12];
    const float* bn4w = (const float*)d_in[13];
    const float* bn4b = (const float*)d_in[14];
    const float* lw1  = (const float*)d_in[15];
    const float* lb1  = (const float*)d_in[16];
    const float* lw2  = (const float*)d_in[17];
    const float* lb2  = (const float*)d_in[18];
    const float* a1   = (const float*)d_in[19];
    const float* a2   = (const float*)d_in[20];
    const float* a3   = (const float*)d_in[21];
    const float* a4   = (const float*)d_in[22];
    float* out = (float*)d_out;

    char* p = (char*)d_ws;
    auto carve = [&](size_t bytes) -> void* {
        void* r = (void*)p;
        p += (bytes + 255) & ~(size_t)255;
        return r;
    };
    int*    hist = (int*)carve((size_t)M_SC * 4);
    int*    ebase = (int*)carve((size_t)M_SC * 4);
    int*    ebuck = (int*)carve((size_t)N_EDGES * 4);
    int*    col  = (int*)carve((size_t)N_EDGES * 4);
    float*  dis  = (float*)carve((size_t)N_NODES * 4);
    int2*   meta = (int2*)carve((size_t)N_NODES * 8);
    int*    bsum = (int*)carve(4096);
    ushort* A    = (ushort*)carve((size_t)N_NODES * HID * 2);
    ushort* B    = (ushort*)carve((size_t)N_NODES * HID * 2);
    float*  th   = (float*)carve((size_t)N_GRAPHS * HID * 4);
    float*  statsr = (float*)carve(6 * 512 * 4);   // 6 arrays x 8 replicas x 64
    float* s1r = statsr,          *ss1r = statsr + 512;
    float* s2r = statsr + 1024,   *ss2r = statsr + 1536;
    float* s3r = statsr + 2048,   *ss3r = statsr + 2560;

    const int SC_BLKS = (M_SC + 1023) / 1024;  // 382

    k_hist<<<B_H, 256, 0, stream>>>(dst4, hist, statsr);
    k_s1<<<SC_BLKS, 256, 0, stream>>>(hist, ebase, bsum, M_SC);
    k_s2<<<1, 256, 0, stream>>>(bsum, SC_BLKS);
    k_bucketize<<<B_H, 256, 0, stream>>>(src4, dst4, ebase, bsum, ebuck);
    k_csr<<<K_B, 256, 0, stream>>>(ebase, bsum, ebuck, col, meta, dis);

    const int NB32 = N_NODES / 32;  // 3125, exact
    k_gemm1<<<NB32, 512, 0, stream>>>(x, W1, dis, A);
    k_agg<<<NB32, 256, 0, stream>>>((const uint4*)A, dis, meta, col, b1, (uint4*)B,
                                    s1r, ss1r);
    k_gemm2<<<NB32, 512, 0, stream>>>(B, s1r, ss1r, bn1w, bn1b, a1, W2, dis, A);
    k_agg<<<NB32, 256, 0, stream>>>((const uint4*)A, dis, meta, col, b2, (uint4*)B,
                                    s2r, ss2r);
    k_pool<<<N_GRAPHS, 256, 0, stream>>>((const uint4*)B, s2r, ss2r, bn2w, bn2b, a2,
                                         lw1, lb1, th, s3r, ss3r);
    k_head<<<1, 512, 0, stream>>>(th, s3r, ss3r, bn3w, bn3b, a3, lw2, lb2,
                                  bn4w, bn4b, a4, out);
}